// Round 1
// baseline (211.003 us; speedup 1.0000x reference)
//
#include <hip/hip_runtime.h>
#include <hip/hip_cooperative_groups.h>

namespace cg = cooperative_groups;

// Problem constants: B=2, T=8, NQ=128, NK=128, DIM_IN=64, DIM_OUT=256
#define C_TANH 2.8853900817779268f   // 2*log2(e): exp(2x) == exp2(C*x)
#define LOG2E  1.4426950408889634f

// Exact f32 tanh via exp2+rcp (2 transc ops).
__device__ __forceinline__ float tanh_exact(float x) {
  float e = __builtin_amdgcn_exp2f(C_TANH * x);
  return 1.0f - 2.0f * __builtin_amdgcn_rcpf(1.0f + e);
}

// Single cooperative kernel, 512 blocks x 256 threads (2 blocks/CU — LDS
// allows 4, so cooperative co-residency is guaranteed).
//
// Phase 1 (== old proj_kernel):
//   blocks [0,256):   k2t[bt][d][k] = tanh(keys[bt,k,:]@Wk[:,d] + bk[d])
//   blocks [256,512): q1t[row][d]   = tanh(query[row,:]@Wq[:,d])
// grid.sync()
// Phase 2 (== old score_kernel): tanh addition formula
//   tanh(q+k) = (ta+tb)/(1+ta*tb); logits pre-scaled by log2e -> exp2 softmax.
//   Block = 4 rows of one bt; wave = one full row. tb slice consumed from LDS
//   in 4 phases of [64][128] (32 KB). LDS/block = 40 KB.
__global__ __launch_bounds__(256, 2) void fused_kernel(
    const float* __restrict__ query, const float* __restrict__ keys,
    const float* __restrict__ Wq, const float* __restrict__ Wk,
    const float* __restrict__ bk, const float* __restrict__ v,
    float* __restrict__ q1t, float* __restrict__ k2t,
    float* __restrict__ out) {
  __shared__ __align__(16) float smem[64 * 128 + 2 * 1024];  // 40 KB

  int tid = threadIdx.x;
  int bid = blockIdx.x;

  // ---------------- Phase 1: projections (writes q1t, k2t) ----------------
  if (bid < 256) {
    float4* krows4 = (float4*)smem;  // 8 key rows x 64 floats = 2 KB alias
    int bt = bid >> 4;
    int kg = bid & 15;
    if (tid < 128)
      krows4[tid] = ((const float4*)(keys + bt * 8192 + kg * 512))[tid];
    __syncthreads();
    int d = tid;
    float acc[8];
    float bias = bk[d];
#pragma unroll
    for (int kk = 0; kk < 8; ++kk) acc[kk] = bias;
#pragma unroll 4
    for (int i4 = 0; i4 < 16; ++i4) {
      float wa = Wk[(i4 * 4 + 0) * 256 + d];   // coalesced across lanes
      float wb = Wk[(i4 * 4 + 1) * 256 + d];
      float wc = Wk[(i4 * 4 + 2) * 256 + d];
      float wd = Wk[(i4 * 4 + 3) * 256 + d];
#pragma unroll
      for (int kk = 0; kk < 8; ++kk) {
        float4 kr = krows4[kk * 16 + i4];      // wave-uniform b128 broadcast
        acc[kk] = fmaf(kr.x, wa, acc[kk]);
        acc[kk] = fmaf(kr.y, wb, acc[kk]);
        acc[kk] = fmaf(kr.z, wc, acc[kk]);
        acc[kk] = fmaf(kr.w, wd, acc[kk]);
      }
    }
#pragma unroll
    for (int kk = 0; kk < 8; ++kk)
      k2t[(bt * 256 + d) * 128 + kg * 8 + kk] = tanh_exact(acc[kk]);
  } else {
    float* qrow = smem;                        // 256 B alias
    int row = bid - 256;
    if (tid < 64) qrow[tid] = query[row * 64 + tid];
    __syncthreads();
    int d = tid;
    float acc = 0.f;
#pragma unroll
    for (int i = 0; i < 64; ++i) acc += qrow[i] * Wq[i * 256 + d];
    q1t[row * 256 + d] = tanh_exact(acc);
  }

  // All phase-1 smem reads done + stores visible device-wide, then grid sync.
  __syncthreads();
  __threadfence();
  cg::this_grid().sync();

  // ---------------- Phase 2: score + softmax ------------------------------
  float*  tb = smem;                           // [64][128], 32 KB
  float2* qv = (float2*)(smem + 64 * 128);     // [4][256],  8 KB

  int wid = tid >> 6;               // wave = row 0..3
  int kk  = tid & 63;               // k-pair index
  int bt  = bid >> 5;               // 512 blocks = 16 bt x 32 row-groups
  int qg  = bid & 31;               // group of 4 q-rows
  int b   = bt >> 3;
  int q0  = qg * 4;                 // base q within [0,128)

  // stage {ta, v'}: 4 rows x 256, coalesced (4 entries/thread)
  for (int i = tid; i < 1024; i += 256) {
    int rr = i >> 8;
    int d  = i & 255;
    qv[i] = make_float2(q1t[(b * 128 + q0 + rr) * 256 + d], v[d] * LOG2E);
  }

  const float* ksrc = k2t + bt * 32768;  // [256][128] tb slice for this bt
  float2 acc = make_float2(0.f, 0.f);

#pragma unroll
  for (int h = 0; h < 4; ++h) {
    __syncthreads();  // previous phase fully consumed before overwrite
    // stage 8192 floats (32 KB) coalesced: 8 float4 per thread
    const float4* src4 = (const float4*)(ksrc + h * 8192);
    float4* dst4 = (float4*)tb;
    for (int i = tid; i < 2048; i += 256) dst4[i] = src4[i];
    __syncthreads();

    const float2* tb2 = (const float2*)tb;  // [64 d][64 k-pairs]
#pragma unroll 8
    for (int d = 0; d < 64; ++d) {
      float2 tav = qv[wid * 256 + h * 64 + d];  // wave-uniform b64 broadcast
      float2 tbv = tb2[d * 64 + kk];            // per-lane b64, 2-way (free)
      float n0 = tav.x + tbv.x;                 // numerator ta+tb
      float n1 = tav.x + tbv.y;
      float d0 = fmaf(tav.x, tbv.x, 1.0f);      // denominator 1+ta*tb >= 0.01
      float d1 = fmaf(tav.x, tbv.y, 1.0f);
      float r0 = n0 * __builtin_amdgcn_rcpf(d0);
      float r1 = n1 * __builtin_amdgcn_rcpf(d1);
      acc.x = fmaf(tav.y, r0, acc.x);
      acc.y = fmaf(tav.y, r1, acc.y);
    }
  }

  // softmax: whole row lives in this wave -> pure 64-lane butterfly
  float s0 = acc.x, s1 = acc.y;     // logits pre-scaled by log2(e)
  float m = fmaxf(s0, s1);
#pragma unroll
  for (int off = 32; off > 0; off >>= 1) m = fmaxf(m, __shfl_xor(m, off, 64));
  float e0 = __builtin_amdgcn_exp2f(s0 - m);
  float e1 = __builtin_amdgcn_exp2f(s1 - m);
  float ssum = e0 + e1;
#pragma unroll
  for (int off = 32; off > 0; off >>= 1) ssum += __shfl_xor(ssum, off, 64);
  float inv = __builtin_amdgcn_rcpf(ssum);

  int row = bt * 128 + q0 + wid;    // output row
  ((float2*)(out + row * 128))[kk] = make_float2(e0 * inv, e1 * inv);
}

extern "C" void kernel_launch(void* const* d_in, const int* in_sizes, int n_in,
                              void* d_out, int out_size, void* d_ws, size_t ws_size,
                              hipStream_t stream) {
  const float* query = (const float*)d_in[0];  // [2,128,64]
  const float* keys  = (const float*)d_in[1];  // [2,8,128,64]
  const float* Wq    = (const float*)d_in[2];  // [64,256]
  const float* Wk    = (const float*)d_in[3];  // [64,256]
  const float* bk    = (const float*)d_in[4];  // [256]
  const float* v     = (const float*)d_in[5];  // [256]
  float* out = (float*)d_out;                  // [2,8,128,128]

  float* ws  = (float*)d_ws;
  float* q1t = ws;            // 256*256    = 65536 floats (tanh of q-proj)
  float* k2t = ws + 65536;    // 16*256*128 = 524288 floats (tanh of k-proj)

  void* args[] = {&query, &keys, &Wq, &Wk, &bk, &v, &q1t, &k2t, &out};
  hipLaunchCooperativeKernel((void*)fused_kernel, dim3(512), dim3(256), args,
                             0, stream);
}

// Round 2
// 88.292 us; speedup vs baseline: 2.3898x; 2.3898x over previous
//
#include <hip/hip_runtime.h>

// Problem constants: B=2, T=8, NQ=128, NK=128, DIM_IN=64, DIM_OUT=256
#define C_TANH 2.8853900817779268f   // 2*log2(e): exp(2x) == exp2(C*x)
#define LOG2E  1.4426950408889634f

// Exact f32 tanh via exp2+rcp (2 transc ops) — used only in proj (1M evals).
__device__ __forceinline__ float tanh_exact(float x) {
  float e = __builtin_amdgcn_exp2f(C_TANH * x);
  return 1.0f - 2.0f * __builtin_amdgcn_rcpf(1.0f + e);
}

// Fused projection kernel, 512 blocks x 256 threads. Outputs are TANH of the
// projections (enables the addition formula in the score kernel):
//   blocks [0,256):   k2t[bt][d][k] = tanh(keys[bt,k,:]@Wk[:,d] + bk[d])
//   blocks [256,512): q1t[row][d]   = tanh(query[row,:]@Wq[:,d])
__global__ __launch_bounds__(256) void proj_kernel(
    const float* __restrict__ query, const float* __restrict__ keys,
    const float* __restrict__ Wq, const float* __restrict__ Wk,
    const float* __restrict__ bk, float* __restrict__ q1t,
    float* __restrict__ k2t) {
  int bid = blockIdx.x;
  int d   = threadIdx.x;
  if (bid < 256) {
    int bt = bid >> 4;
    int kg = bid & 15;
    __shared__ float4 krows4[128];  // 8 key rows x 64 floats
    if (threadIdx.x < 128)
      krows4[threadIdx.x] =
          ((const float4*)(keys + bt * 8192 + kg * 512))[threadIdx.x];
    __syncthreads();
    float acc[8];
    float bias = bk[d];
#pragma unroll
    for (int kk = 0; kk < 8; ++kk) acc[kk] = bias;
#pragma unroll 4
    for (int i4 = 0; i4 < 16; ++i4) {
      float wa = Wk[(i4 * 4 + 0) * 256 + d];   // coalesced across lanes
      float wb = Wk[(i4 * 4 + 1) * 256 + d];
      float wc = Wk[(i4 * 4 + 2) * 256 + d];
      float wd = Wk[(i4 * 4 + 3) * 256 + d];
#pragma unroll
      for (int kk = 0; kk < 8; ++kk) {
        float4 kr = krows4[kk * 16 + i4];      // wave-uniform b128 broadcast
        acc[kk] = fmaf(kr.x, wa, acc[kk]);
        acc[kk] = fmaf(kr.y, wb, acc[kk]);
        acc[kk] = fmaf(kr.z, wc, acc[kk]);
        acc[kk] = fmaf(kr.w, wd, acc[kk]);
      }
    }
#pragma unroll
    for (int kk = 0; kk < 8; ++kk)
      k2t[(bt * 256 + d) * 128 + kg * 8 + kk] = tanh_exact(acc[kk]);
  } else {
    int row = bid - 256;
    __shared__ float qrow[64];
    if (threadIdx.x < 64) qrow[threadIdx.x] = query[row * 64 + threadIdx.x];
    __syncthreads();
    float acc = 0.f;
#pragma unroll
    for (int i = 0; i < 64; ++i) acc += qrow[i] * Wq[i * 256 + d];
    q1t[row * 256 + d] = tanh_exact(acc);
  }
}

// Score+softmax via tanh addition formula:
//   tanh(q+k) = (ta + tb) / (1 + ta*tb),   ta=tanh(q), tb=tanh(k)  [1 rcp/elem]
// logits'_k = sum_d v'_d * r_dk, v' = v*log2e -> softmax directly in exp2.
// Block = 4 rows of one bt (512 blocks); wave = one full row (lane = k-pair).
// tb slice [256][128] is consumed from LDS in 4 phases of [64][128] (32 KB),
// cutting k2t global traffic 268 MB -> 64 MB (tile reused by 4 rows).
// LDS/block = 32 KB tb + 8 KB qv = 40 KB -> 4 blocks/CU = 16 waves/CU.
__global__ __launch_bounds__(256, 4) void score_kernel(
    const float* __restrict__ q1t, const float* __restrict__ v,
    const float* __restrict__ k2t, float* __restrict__ out) {
  __shared__ float  tb[64 * 128];   // 32 KB: current d-quarter of the k-slice
  __shared__ float2 qv[4 * 256];    // 8 KB: {ta, v*log2e} for the 4 rows
  int tid = threadIdx.x;
  int wid = tid >> 6;               // wave = row 0..3
  int kk  = tid & 63;               // k-pair index
  int blk = blockIdx.x;             // 512 blocks = 16 bt x 32 row-groups
  int bt  = blk >> 5;
  int qg  = blk & 31;               // group of 4 q-rows
  int b   = bt >> 3;
  int q0  = qg * 4;                 // base q within [0,128)

  // stage {ta, v'}: 4 rows x 256, coalesced (4 entries/thread)
  for (int i = tid; i < 1024; i += 256) {
    int rr = i >> 8;
    int d  = i & 255;
    qv[i] = make_float2(q1t[(b * 128 + q0 + rr) * 256 + d], v[d] * LOG2E);
  }

  const float* ksrc = k2t + bt * 32768;  // [256][128] tb slice for this bt
  float2 acc = make_float2(0.f, 0.f);

#pragma unroll
  for (int h = 0; h < 4; ++h) {
    __syncthreads();  // previous phase fully consumed before overwrite
    // stage 8192 floats (32 KB) coalesced: 8 float4 per thread
    const float4* src4 = (const float4*)(ksrc + h * 8192);
    float4* dst4 = (float4*)tb;
    for (int i = tid; i < 2048; i += 256) dst4[i] = src4[i];
    __syncthreads();

    const float2* tb2 = (const float2*)tb;  // [64 d][64 k-pairs]
#pragma unroll 8
    for (int d = 0; d < 64; ++d) {
      float2 tav = qv[wid * 256 + h * 64 + d];  // wave-uniform b64 broadcast
      float2 tbv = tb2[d * 64 + kk];            // per-lane b64
      float n0 = tav.x + tbv.x;                 // numerator ta+tb
      float n1 = tav.x + tbv.y;
      float d0 = fmaf(tav.x, tbv.x, 1.0f);      // denominator 1+ta*tb >= 0.01
      float d1 = fmaf(tav.x, tbv.y, 1.0f);
      float r0 = n0 * __builtin_amdgcn_rcpf(d0);
      float r1 = n1 * __builtin_amdgcn_rcpf(d1);
      acc.x = fmaf(tav.y, r0, acc.x);
      acc.y = fmaf(tav.y, r1, acc.y);
    }
  }

  // softmax: whole row lives in this wave -> pure 64-lane butterfly
  float s0 = acc.x, s1 = acc.y;     // logits pre-scaled by log2(e)
  float m = fmaxf(s0, s1);
#pragma unroll
  for (int off = 32; off > 0; off >>= 1) m = fmaxf(m, __shfl_xor(m, off, 64));
  float e0 = __builtin_amdgcn_exp2f(s0 - m);
  float e1 = __builtin_amdgcn_exp2f(s1 - m);
  float ssum = e0 + e1;
#pragma unroll
  for (int off = 32; off > 0; off >>= 1) ssum += __shfl_xor(ssum, off, 64);
  float inv = __builtin_amdgcn_rcpf(ssum);

  int row = bt * 128 + q0 + wid;    // output row
  ((float2*)(out + row * 128))[kk] = make_float2(e0 * inv, e1 * inv);
}

extern "C" void kernel_launch(void* const* d_in, const int* in_sizes, int n_in,
                              void* d_out, int out_size, void* d_ws, size_t ws_size,
                              hipStream_t stream) {
  const float* query = (const float*)d_in[0];  // [2,128,64]
  const float* keys  = (const float*)d_in[1];  // [2,8,128,64]
  const float* Wq    = (const float*)d_in[2];  // [64,256]
  const float* Wk    = (const float*)d_in[3];  // [64,256]
  const float* bk    = (const float*)d_in[4];  // [256]
  const float* v     = (const float*)d_in[5];  // [256]
  float* out = (float*)d_out;                  // [2,8,128,128]

  float* ws  = (float*)d_ws;
  float* q1t = ws;            // 256*256    = 65536 floats (tanh of q-proj)
  float* k2t = ws + 65536;    // 16*256*128 = 524288 floats (tanh of k-proj)

  proj_kernel<<<512, 256, 0, stream>>>(query, keys, Wq, Wk, bk, q1t, k2t);
  score_kernel<<<512, 256, 0, stream>>>(q1t, v, k2t, out);
}